// Round 1
// baseline (492.904 us; speedup 1.0000x reference)
//
#include <hip/hip_runtime.h>

// ComplexMultiheadAttention on MI355X (gfx950)  B=2, L=2048, E=1024, H=16, D=64
// R7: gemm_qkv rewritten as 256x256-tile 8-phase schedule (plain-HIP port of
// the HK/m201 template): 512 thr / 8 waves (2Mx4N), BK=64, LDS 128 KiB as
// 2 dbuf x {A,B} x {half0,half1} 16KB halves. Gray-ordered quadrant phases
// (0,0)->(0,1)->(1,1)->(1,0); one half-tile staged per phase via
// global_load_lds x2/thread; counted s_waitcnt vmcnt(4) (never 0 in main
// loop) placed BEFORE the end-of-phase barrier (barrier globalizes the
// per-wave load guarantee); last K-tile peeled with exact drains 2->0.
// s_setprio(1) around each 16-MFMA cluster (T5 pays only on phase-split
// schedules). MFMA order per acc element identical to R6 -> same numerics.
// attn / conv_x / conv_w / gemm_oproj unchanged from R6.

#define LL 2048
#define EE 1024
#define HH 16
#define BL 4096   // B*L
#define KK 2048   // GEMM K (re||im)

typedef __attribute__((ext_vector_type(8))) short bf16x8;
typedef __attribute__((ext_vector_type(4))) float f32x4;
typedef unsigned short u16;

__device__ __forceinline__ u16 f2bf(float x) {
    unsigned u = __builtin_bit_cast(unsigned, x);
    u += 0x7fff + ((u >> 16) & 1);          // RNE
    return (u16)(u >> 16);
}

__device__ __forceinline__ void gl2lds16(const void* g, void* l) {
    __builtin_amdgcn_global_load_lds((const __attribute__((address_space(1))) void*)g,
                                     (__attribute__((address_space(3))) void*)l, 16, 0, 0);
}

// ---------------------------------------------------------------------------
// Merged fp32->bf16 conversion: 6 activation tensors, grid (4096, 6)
// ---------------------------------------------------------------------------
struct ConvXArgs { const float* src[6]; u16* dst[6]; };
__global__ void conv_x(ConvXArgs a) {
    const int z = blockIdx.y;
    int i = blockIdx.x * 256 + threadIdx.x;     // 1,048,576 float4 groups exactly
    float4 v = ((const float4*)a.src[z])[i];
    ushort4 o;
    o.x = f2bf(v.x); o.y = f2bf(v.y); o.z = f2bf(v.z); o.w = f2bf(v.w);
    ((ushort4*)a.dst[z])[i] = o;
}

// ---------------------------------------------------------------------------
// Merged W2 build: 4 weight pairs, grid (4096, 4)
// W2 bf16 [2048 n][2048 k]: n<1024: [Wr | -Wi] ; n>=1024: [Wi | Wr]
// ---------------------------------------------------------------------------
struct ConvWArgs { const float* wr[4]; const float* wi[4]; u16* w2[4]; };
__global__ void conv_w(ConvWArgs a) {
    const int z = blockIdx.y;
    int i = blockIdx.x * 256 + threadIdx.x;     // 2048*512 groups exactly
    int n = i >> 9, k = (i & 511) << 2;
    bool nh = n >= EE, kh = k >= EE;
    int nn = n & (EE - 1), kk = k & (EE - 1);
    const float* src = nh ? (kh ? a.wr[z] : a.wi[z]) : (kh ? a.wi[z] : a.wr[z]);
    float sgn = (!nh && kh) ? -1.0f : 1.0f;
    float4 v = *(const float4*)(src + nn * EE + kk);
    ushort4 o;
    o.x = f2bf(v.x * sgn); o.y = f2bf(v.y * sgn);
    o.z = f2bf(v.z * sgn); o.w = f2bf(v.w * sgn);
    *(ushort4*)(a.w2[z] + n * KK + k) = o;
}

// ---------------------------------------------------------------------------
// Old-style GEMM K-loop core (kept for gemm_oproj), BK=64: As/Bs [128][64] u16
// ---------------------------------------------------------------------------
#define GEMM_BK64_LOOP(Ar, Ai, B2)                                             \
    for (int k0 = 0; k0 < KK; k0 += 64) {                                      \
        const u16* Asrc = (k0 < EE) ? (Ar + k0) : (Ai + (k0 - EE));            \
        const u16* Bsrc = B2 + k0;                                             \
        __syncthreads();                                                       \
        {                                                                      \
            int rr = lane >> 3, cg = (lane & 7) ^ rr;                          \
            for (int t = 0; t < 4; t++) {                                      \
                int s = wave * 4 + t;                                          \
                int r0 = s * 8 + rr;                                           \
                gl2lds16(Asrc + (size_t)(m0 + r0) * EE + cg * 8, &As[s * 512]);\
                gl2lds16(Bsrc + (size_t)(n0 + r0) * KK + cg * 8, &Bs[s * 512]);\
            }                                                                  \
        }                                                                      \
        __syncthreads();                                                       \
        for (int ks2 = 0; ks2 < 2; ks2++) {                                    \
            bf16x8 a[4], b[4];                                                 \
            for (int t = 0; t < 4; t++) {                                      \
                int ra = wm + t * 16 + l16;                                    \
                a[t] = *(const bf16x8*)&As[ra * 64 + (((ks2 * 4 + quad) ^ (ra & 7)) << 3)]; \
                int rb = wn + t * 16 + l16;                                    \
                b[t] = *(const bf16x8*)&Bs[rb * 64 + (((ks2 * 4 + quad) ^ (rb & 7)) << 3)]; \
            }                                                                  \
            for (int i = 0; i < 4; i++)                                        \
                for (int j = 0; j < 4; j++)                                    \
                    acc[i][j] = __builtin_amdgcn_mfma_f32_16x16x32_bf16(a[i], b[j], acc[i][j], 0, 0, 0); \
        }                                                                      \
    }

// ---------------------------------------------------------------------------
// 256x256 8-phase QKV projection GEMM: grid (8, 16, 3), 512 threads.
// z=0 (Q) / z=1 (K): epilogue -> ws[bh][l][128] bf16 (Q scaled by oscale)
// z=2 (V):           epilogue -> ws[bh][128][2048] bf16 (transposed)
// ---------------------------------------------------------------------------
struct QKVArgs {
    const u16* Ar[3]; const u16* Ai[3]; const u16* B2[3];
    const float* br[3]; const float* bi[3];
    u16* out[3];
    float oscale[3];
};

// barriers: memory clobber pins LDS reads/writes into their phase; the
// vmcnt precedes s_barrier inside ONE asm so no load can slip between them.
#define BAR      asm volatile("s_barrier" ::: "memory")
#define BARW(N)  asm volatile("s_waitcnt vmcnt(" #N ")\n\ts_barrier" ::: "memory")

// register-fragment loads from swizzled LDS halves (conflict-free:
// phys chunk = (s*4+quad) ^ (row&7), row&7 == l16&7 here)
#define LOAD_A(QM)                                                             \
    { const u16* base_ = &AB[buf][0][QM][0];                                   \
      _Pragma("unroll") for (int i_ = 0; i_ < 4; i_++) {                       \
          int row_ = wr * 64 + i_ * 16 + l16;                                  \
          _Pragma("unroll") for (int s_ = 0; s_ < 2; s_++) {                   \
              int ph_ = (s_ * 4 + quad) ^ (l16 & 7);                           \
              afr[i_][s_] = *(const bf16x8*)&base_[row_ * 64 + ph_ * 8];       \
          } } }

#define LOAD_B(QN)                                                             \
    { const u16* base_ = &AB[buf][1][QN][0];                                   \
      _Pragma("unroll") for (int j_ = 0; j_ < 2; j_++) {                       \
          int row_ = wc * 32 + j_ * 16 + l16;                                  \
          _Pragma("unroll") for (int s_ = 0; s_ < 2; s_++) {                   \
              int ph_ = (s_ * 4 + quad) ^ (l16 & 7);                           \
              bfr[QN][j_][s_] = *(const bf16x8*)&base_[row_ * 64 + ph_ * 8];   \
          } } }

#define MMA(QM, QN)                                                            \
    { __builtin_amdgcn_s_setprio(1);                                           \
      _Pragma("unroll") for (int s_ = 0; s_ < 2; s_++)                         \
          _Pragma("unroll") for (int i_ = 0; i_ < 4; i_++)                     \
              _Pragma("unroll") for (int j_ = 0; j_ < 2; j_++)                 \
                  acc[QM * 4 + i_][QN * 2 + j_] =                              \
                      __builtin_amdgcn_mfma_f32_16x16x32_bf16(                 \
                          afr[i_][s_], bfr[QN][j_][s_],                        \
                          acc[QM * 4 + i_][QN * 2 + j_], 0, 0, 0);             \
      __builtin_amdgcn_s_setprio(0); }

// stage one 128x64 half-tile (16 KB) = 2 gl2lds/thread; LDS dest linear,
// source chunk pre-swizzled so LDS[row][c] = G[row][c ^ (row&7)].
#define STAGE_A(BUF, HALF, K0)                                                 \
    { const u16* S_ = ((K0) < EE) ? (Apr + (K0)) : (Api + ((K0) - EE));        \
      int rl_ = wv * 8 + (lane >> 3);                                          \
      int cg_ = ((lane & 7) ^ (lane >> 3)) * 8;                                \
      gl2lds16(S_ + (size_t)(m0 + (HALF) * 128 + rl_) * EE + cg_,              \
               &AB[BUF][0][HALF][wv * 512]);                                   \
      gl2lds16(S_ + (size_t)(m0 + (HALF) * 128 + rl_ + 64) * EE + cg_,         \
               &AB[BUF][0][HALF][wv * 512 + 4096]); }

#define STAGE_B(BUF, HALF, K0)                                                 \
    { const u16* S_ = Bp + (K0);                                               \
      int rl_ = wv * 8 + (lane >> 3);                                          \
      int cg_ = ((lane & 7) ^ (lane >> 3)) * 8;                                \
      gl2lds16(S_ + (size_t)(n0 + (HALF) * 128 + rl_) * (size_t)KK + cg_,      \
               &AB[BUF][1][HALF][wv * 512]);                                   \
      gl2lds16(S_ + (size_t)(n0 + (HALF) * 128 + rl_ + 64) * (size_t)KK + cg_, \
               &AB[BUF][1][HALF][wv * 512 + 4096]); }

__launch_bounds__(512, 2)
__global__ void gemm_qkv(QKVArgs args) {
    // [buf][A=0/B=1][half][128*64] = 128 KiB
    __shared__ __attribute__((aligned(16))) u16 AB[2][2][2][8192];

    const int z = blockIdx.z;
    const u16* __restrict__ Apr = args.Ar[z];
    const u16* __restrict__ Api = args.Ai[z];
    const u16* __restrict__ Bp  = args.B2[z];

    const int tid = threadIdx.x, wv = tid >> 6, lane = tid & 63;
    const int quad = lane >> 4, l16 = lane & 15;
    const int m0 = blockIdx.y * 256, n0 = blockIdx.x * 256;
    const int wr = wv >> 2, wc = wv & 3;   // 2M x 4N waves, 128x64 out each

    f32x4 acc[8][4] = {};
    bf16x8 afr[4][2];        // current A-half frags: [rowfrag][ksub]
    bf16x8 bfr[2][2][2];     // both B-halves:        [qn][colfrag][ksub]

    // prologue: stage tile 0 halves in consumption-guard order A0,B0,B1,A1
    STAGE_A(0, 0, 0); STAGE_B(0, 0, 0); STAGE_B(0, 1, 0); STAGE_A(0, 1, 0);
    BARW(4);                 // A0,B0 of tile 0 resident everywhere

    for (int T = 0; T < 31; T++) {
        const int buf = T & 1, nb = buf ^ 1;
        const int k1 = T * 64 + 64;
        // p0: quadrant (0,0) — stage A0 of T+1
        LOAD_A(0); LOAD_B(0);
        STAGE_A(nb, 0, k1);
        BAR;
        MMA(0, 0);
        BARW(4);             // B1 of T resident
        // p1: (0,1) — stage B0 of T+1
        LOAD_B(1);
        STAGE_B(nb, 0, k1);
        BAR;
        MMA(0, 1);
        BARW(4);             // A1 of T resident
        // p2: (1,1) — stage B1 of T+1
        LOAD_A(1);
        STAGE_B(nb, 1, k1);
        BAR;
        MMA(1, 1);
        BAR;
        // p3: (1,0) — stage A1 of T+1 (operands already in regs)
        STAGE_A(nb, 1, k1);
        BAR;
        MMA(1, 0);
        BARW(4);             // A0,B0 of T+1 resident
    }
    {   // peeled last tile T=31 (buf=1, nothing left to stage): exact drains
        const int buf = 1;
        LOAD_A(0); LOAD_B(0);
        MMA(0, 0);
        BARW(2);             // B1 resident
        LOAD_B(1);
        MMA(0, 1);
        BARW(0);             // A1 resident
        LOAD_A(1);
        MMA(1, 1);
        MMA(1, 0);
    }

    // epilogue
    const float* __restrict__ br_ = args.br[z];
    const float* __restrict__ bi_ = args.bi[z];
    u16* __restrict__ out = args.out[z];
    const float oscale = args.oscale[z];

    #pragma unroll
    for (int j = 0; j < 4; j++) {
        int gn = n0 + (j >> 1) * 128 + wc * 32 + (j & 1) * 16 + l16;
        int ri = gn >> 10, e = gn & 1023;
        float bias = ri ? bi_[e] : br_[e];
        int h = e >> 6, d = e & 63;
        #pragma unroll
        for (int i = 0; i < 8; i++) {
            int gmb = m0 + (i >> 2) * 128 + wr * 64 + (i & 3) * 16 + quad * 4;
            #pragma unroll
            for (int r = 0; r < 4; r++) {
                int gm = gmb + r;
                float v = (acc[i][j][r] + bias) * oscale;
                int b = gm >> 11, l = gm & 2047;
                if (z < 2)
                    out[((size_t)(b * HH + h) * LL + l) * 128 + ri * 64 + d] = f2bf(v);
                else
                    out[((size_t)(b * HH + h) * 128 + ri * 64 + d) * LL + l] = f2bf(v);
            }
        }
    }
}

// ---------------------------------------------------------------------------
// Output projection GEMM -> d_out fp32 [2][4096][1024]  (unchanged 128² path)
// ---------------------------------------------------------------------------
__launch_bounds__(256, 2)
__global__ void gemm_oproj(const u16* __restrict__ Ar, const u16* __restrict__ Ai,
                           const u16* __restrict__ B2,
                           const float* __restrict__ br, const float* __restrict__ bi,
                           float* __restrict__ out)
{
    __shared__ __attribute__((aligned(16))) u16 As[128 * 64];
    __shared__ __attribute__((aligned(16))) u16 Bs[128 * 64];

    const int tid = threadIdx.x, wave = tid >> 6, lane = tid & 63;
    const int quad = lane >> 4, l16 = lane & 15;
    const int m0 = blockIdx.y * 128, n0 = blockIdx.x * 128;
    const int wm = (wave >> 1) * 64, wn = (wave & 1) * 64;

    f32x4 acc[4][4] = {};

    GEMM_BK64_LOOP(Ar, Ai, B2)

    for (int j = 0; j < 4; j++) {
        int gn = n0 + wn + j * 16 + l16;
        int ri = gn >> 10, e = gn & 1023;
        float bias = ri ? bi[e] : br[e];
        for (int i = 0; i < 4; i++) {
            int gmb = m0 + wm + i * 16 + quad * 4;
            for (int r = 0; r < 4; r++) {
                int gm = gmb + r;
                out[ri * (BL * EE) + gm * EE + e] = acc[i][j][r] + bias;
            }
        }
    }
}

// ---------------------------------------------------------------------------
// Flash attention, BQ=64 (grid 32x32, 3 blocks/CU): transposed-S, online
// softmax in log2 domain (math VERBATIM from the known-good R2 kernel).
// q_ws/k_ws: bf16 [bh][l][128] (Q pre-scaled by 0.125*log2e); v_ws: [bh][128][2048]
// ---------------------------------------------------------------------------
__launch_bounds__(256, 3)
__global__ void attn(const u16* __restrict__ q_ws, const u16* __restrict__ k_ws,
                     const u16* __restrict__ v_ws,
                     u16* __restrict__ o_r, u16* __restrict__ o_i)
{
    __shared__ __attribute__((aligned(16))) u16 kbuf[2][64 * 128];  // 2x16 KB
    __shared__ __attribute__((aligned(16))) u16 vbuf[128 * 64];     // 16 KB
    __shared__ __attribute__((aligned(16))) float red_sh[4][16];

    const int tid = threadIdx.x, wave = tid >> 6, lane = tid & 63;
    const int quad = lane >> 4, l16 = lane & 15;
    const int q0 = blockIdx.x * 64, bh = blockIdx.y;

    // Q fragments (B-operand layout: row = l16, k = quad*8+j); wave owns 16 q rows
    bf16x8 qf[4];
    {
        const u16* qp = q_ws + (size_t)(bh * LL + q0 + wave * 16 + l16) * 128 + quad * 8;
        for (int ks = 0; ks < 4; ks++)
            qf[ks] = *(const bf16x8*)(qp + ks * 32);
    }

    auto stage_k = [&](int nb, int kv0) {
        for (int t = 0; t < 4; t++) {
            int s = wave * 4 + t;
            int row = s * 4 + (lane >> 4);
            int cg = (lane & 15) ^ (row & 15);
            gl2lds16(k_ws + (size_t)(bh * LL + kv0 + row) * 128 + cg * 8, &kbuf[nb][s * 512]);
        }
    };
    auto stage_v = [&](int kv0) {
        for (int t = 0; t < 4; t++) {
            int s = wave * 4 + t;
            int row = s * 8 + (lane >> 3);
            int cg = (lane & 7) ^ (row & 7);
            gl2lds16(v_ws + (size_t)(bh * 128 + row) * LL + kv0 + cg * 8, &vbuf[s * 512]);
        }
    };

    stage_k(0, 0);
    stage_v(0);
    stage_k(1, 64);
    __syncthreads();

    f32x4 oacc[8] = {};
    float m_st = -__builtin_inff();
    float l_st = 0.f;

    for (int N = 0; N < 32; N++) {
        const int cur = N & 1;
        u16* K = kbuf[cur];

        // ---- S^T[64 kv][16 q] = K . Q^T ----
        f32x4 s[4] = {};
        for (int ks = 0; ks < 4; ks++) {
            bf16x8 kf[4];
            for (int mt = 0; mt < 4; mt++) {
                int row = mt * 16 + l16;
                int cl = (ks * 4 + quad) ^ (row & 15);
                kf[mt] = *(const bf16x8*)&K[row * 128 + cl * 8];
            }
            for (int mt = 0; mt < 4; mt++)
                s[mt] = __builtin_amdgcn_mfma_f32_16x16x32_bf16(kf[mt], qf[ks], s[mt], 0, 0, 0);
        }

        // ---- online softmax (log2 domain); q = l16, kv = mt*16+quad*4+r ----
        bool changed = false;
        float alpha;
        {
            float mx = -__builtin_inff();
            for (int mt = 0; mt < 4; mt++)
                for (int r = 0; r < 4; r++)
                    mx = fmaxf(mx, s[mt][r]);
            mx = fmaxf(mx, __shfl_xor(mx, 16, 64));
            mx = fmaxf(mx, __shfl_xor(mx, 32, 64));
            float mnew = fmaxf(m_st, mx);
            changed = (mnew != m_st);
            alpha = __builtin_amdgcn_exp2f(m_st - mnew);
            m_st = mnew;
            float sum = 0.f;
            for (int mt = 0; mt < 4; mt++)
                for (int r = 0; r < 4; r++) {
                    float p = __builtin_amdgcn_exp2f(s[mt][r] - mnew);
                    s[mt][r] = p;
                    sum += p;
                }
            sum += __shfl_xor(sum, 16, 64);
            sum += __shfl_xor(sum, 32, 64);
            l_st = l_st * alpha + sum;
            if (quad == 0) red_sh[wave][l16] = alpha;
        }
        __syncthreads();   // barrier A: K[cur] reads done; drains prev async loads

        // ---- P (A-layout [16 q][64 kv]) into own slice of kbuf[cur] ----
        u16* P = kbuf[cur] + wave * 1024;
        for (int mt = 0; mt < 4; mt++) {
            int q = l16;
            int cg = mt * 2 + (quad >> 1);
            int cl = cg ^ (q & 7);
            ushort4 pk;
            pk.x = f2bf(s[mt][0]); pk.y = f2bf(s[mt][1]);
            pk.z = f2bf(s[mt][2]); pk.w = f2bf(s[mt][3]);
            *(ushort4*)&P[q * 64 + cl * 8 + (quad & 1) * 4] = pk;
        }

        // ---- O rescale (skip when running max unchanged wave-wide) ----
        if (__any(changed)) {
            f32x4 av = *(const f32x4*)&red_sh[wave][quad * 4];
            for (int nt = 0; nt < 8; nt++)
                oacc[nt] *= av;
        }

        // ---- O += P @ V ----
        for (int ks = 0; ks < 2; ks++) {
            int clp = (ks * 4 + quad) ^ (l16 & 7);
            bf16x8 pf = *(const bf16x8*)&P[l16 * 64 + clp * 8];
            for (int nt = 0; nt < 8; nt++) {
                int row = nt * 16 + l16;
                int cl = (ks * 4 + quad) ^ (row & 7);
                bf16x8 vf = *(const bf16x8*)&vbuf[row * 64 + cl * 8];
                oacc[nt] = __builtin_amdgcn_mfma_f32_16x16x32_bf16(pf, vf, oacc[nt], 0, 0, 0);
            }
        }
        __syncthreads();   // barrier B: PV done everywhere; P dead, vbuf free

        if (N + 2 < 32) stage_k(cur, (N + 2) * 64);   // into region P occupied
        if (N + 1 < 32) stage_v((N + 1) * 64);
    }

    // ---- epilogue: O /= l, write bf16 o_r/o_i [4096][1024] ----
    if (quad == 0) red_sh[wave][l16] = l_st;
    __syncthreads();
    f32x4 lv = *(const f32x4*)&red_sh[wave][quad * 4];
    f32x4 inv;
    for (int r = 0; r < 4; r++) inv[r] = 1.0f / lv[r];
    const int b = bh >> 4, h = bh & 15;
    for (int nt = 0; nt < 8; nt++) {
        int d2 = nt * 16 + l16;
        u16* op = (d2 < 64) ? o_r : o_i;
        int col = h * 64 + (d2 & 63);
        for (int r = 0; r < 4; r++) {
            int l = q0 + wave * 16 + quad * 4 + r;
            op[(size_t)(b * LL + l) * EE + col] = f2bf(oacc[nt][r] * inv[r]);
        }
    }
}

// ---------------------------------------------------------------------------
extern "C" void kernel_launch(void* const* d_in, const int* in_sizes, int n_in,
                              void* d_out, int out_size, void* d_ws, size_t ws_size,
                              hipStream_t stream) {
    const float* bq_r = (const float*)d_in[8];
    const float* bq_i = (const float*)d_in[9];
    const float* bk_r = (const float*)d_in[12];
    const float* bk_i = (const float*)d_in[13];
    const float* bv_r = (const float*)d_in[16];
    const float* bv_i = (const float*)d_in[17];
    const float* bo_r = (const float*)d_in[20];
    const float* bo_i = (const float*)d_in[21];

    u16* ws = (u16*)d_ws;
    const size_t XN = 4194304;          // 4096*1024 elements (= 2048*2048)
    u16* xqr = ws;            u16* xqi = xqr + XN;
    u16* xkr = xqi + XN;      u16* xki = xkr + XN;
    u16* xvr = xki + XN;      u16* xvi = xvr + XN;
    u16* w2q = xvi + XN;
    u16* w2k = w2q + XN;
    u16* w2v = w2k + XN;
    u16* w2o = w2v + XN;
    u16* q_ws = w2o + XN;               // 32*2048*128 = 8,388,608
    u16* k_ws = q_ws + 8388608;
    u16* v_ws = k_ws + 8388608;
    u16* o_r = xqr;                     // X regions dead after QKV GEMMs
    u16* o_i = xqr + XN;

    dim3 blk(256);

    ConvXArgs cx;
    cx.src[0] = (const float*)d_in[0]; cx.dst[0] = xqr;
    cx.src[1] = (const float*)d_in[1]; cx.dst[1] = xqi;
    cx.src[2] = (const float*)d_in[2]; cx.dst[2] = xkr;
    cx.src[3] = (const float*)d_in[3]; cx.dst[3] = xki;
    cx.src[4] = (const float*)d_in[4]; cx.dst[4] = xvr;
    cx.src[5] = (const float*)d_in[5]; cx.dst[5] = xvi;
    conv_x<<<dim3(4096, 6), blk, 0, stream>>>(cx);

    ConvWArgs cw;
    cw.wr[0] = (const float*)d_in[6];  cw.wi[0] = (const float*)d_in[7];  cw.w2[0] = w2q;
    cw.wr[1] = (const float*)d_in[10]; cw.wi[1] = (const float*)d_in[11]; cw.w2[1] = w2k;
    cw.wr[2] = (const float*)d_in[14]; cw.wi[2] = (const float*)d_in[15]; cw.w2[2] = w2v;
    cw.wr[3] = (const float*)d_in[18]; cw.wi[3] = (const float*)d_in[19]; cw.w2[3] = w2o;
    conv_w<<<dim3(4096, 4), blk, 0, stream>>>(cw);

    const float QSCALE = 0.125f * 1.44269504088896f;   // 1/sqrt(D) * log2(e)
    QKVArgs qa;
    qa.Ar[0] = xqr; qa.Ai[0] = xqi; qa.B2[0] = w2q; qa.br[0] = bq_r; qa.bi[0] = bq_i; qa.out[0] = q_ws; qa.oscale[0] = QSCALE;
    qa.Ar[1] = xkr; qa.Ai[1] = xki; qa.B2[1] = w2k; qa.br[1] = bk_r; qa.bi[1] = bk_i; qa.out[1] = k_ws; qa.oscale[1] = 1.0f;
    qa.Ar[2] = xvr; qa.Ai[2] = xvi; qa.B2[2] = w2v; qa.br[2] = bv_r; qa.bi[2] = bv_i; qa.out[2] = v_ws; qa.oscale[2] = 1.0f;
    gemm_qkv<<<dim3(8, 16, 3), dim3(512), 0, stream>>>(qa);

    attn<<<dim3(32, 32), blk, 0, stream>>>(q_ws, k_ws, v_ws, o_r, o_i);

    gemm_oproj<<<dim3(16, 32), blk, 0, stream>>>(o_r, o_i, w2o, bo_r, bo_i, (float*)d_out);
}

// Round 2
// 486.279 us; speedup vs baseline: 1.0136x; 1.0136x over previous
//
#include <hip/hip_runtime.h>

// ComplexMultiheadAttention on MI355X (gfx950)  B=2, L=2048, E=1024, H=16, D=64
// R8: gemm_qkv 8-phase schedule corrected to the verified m201 wait structure:
// 2 K-tiles per iteration (even->buf0, odd->buf1), ONE barrier per phase,
// stages issued one full phase after the staged region's last ds-read
// (race-free via the phase barrier), and counted vmcnt(8) ONLY at phases 4
// and 8 -- each wait covers loads issued 6+ phases earlier (T4: loads span
// barriers, never drain to 0 in the main loop). Prologue stages tiles 0+1,
// vmcnt(8); peeled last iteration drains with a single vmcnt(0).
// MFMA order per acc element identical to R6/R7 -> same numerics.
// attn / conv_x / conv_w / gemm_oproj unchanged.

#define LL 2048
#define EE 1024
#define HH 16
#define BL 4096   // B*L
#define KK 2048   // GEMM K (re||im)

typedef __attribute__((ext_vector_type(8))) short bf16x8;
typedef __attribute__((ext_vector_type(4))) float f32x4;
typedef unsigned short u16;

__device__ __forceinline__ u16 f2bf(float x) {
    unsigned u = __builtin_bit_cast(unsigned, x);
    u += 0x7fff + ((u >> 16) & 1);          // RNE
    return (u16)(u >> 16);
}

__device__ __forceinline__ void gl2lds16(const void* g, void* l) {
    __builtin_amdgcn_global_load_lds((const __attribute__((address_space(1))) void*)g,
                                     (__attribute__((address_space(3))) void*)l, 16, 0, 0);
}

// ---------------------------------------------------------------------------
// Merged fp32->bf16 conversion: 6 activation tensors, grid (4096, 6)
// ---------------------------------------------------------------------------
struct ConvXArgs { const float* src[6]; u16* dst[6]; };
__global__ void conv_x(ConvXArgs a) {
    const int z = blockIdx.y;
    int i = blockIdx.x * 256 + threadIdx.x;     // 1,048,576 float4 groups exactly
    float4 v = ((const float4*)a.src[z])[i];
    ushort4 o;
    o.x = f2bf(v.x); o.y = f2bf(v.y); o.z = f2bf(v.z); o.w = f2bf(v.w);
    ((ushort4*)a.dst[z])[i] = o;
}

// ---------------------------------------------------------------------------
// Merged W2 build: 4 weight pairs, grid (4096, 4)
// W2 bf16 [2048 n][2048 k]: n<1024: [Wr | -Wi] ; n>=1024: [Wi | Wr]
// ---------------------------------------------------------------------------
struct ConvWArgs { const float* wr[4]; const float* wi[4]; u16* w2[4]; };
__global__ void conv_w(ConvWArgs a) {
    const int z = blockIdx.y;
    int i = blockIdx.x * 256 + threadIdx.x;     // 2048*512 groups exactly
    int n = i >> 9, k = (i & 511) << 2;
    bool nh = n >= EE, kh = k >= EE;
    int nn = n & (EE - 1), kk = k & (EE - 1);
    const float* src = nh ? (kh ? a.wr[z] : a.wi[z]) : (kh ? a.wi[z] : a.wr[z]);
    float sgn = (!nh && kh) ? -1.0f : 1.0f;
    float4 v = *(const float4*)(src + nn * EE + kk);
    ushort4 o;
    o.x = f2bf(v.x * sgn); o.y = f2bf(v.y * sgn);
    o.z = f2bf(v.z * sgn); o.w = f2bf(v.w * sgn);
    *(ushort4*)(a.w2[z] + n * KK + k) = o;
}

// ---------------------------------------------------------------------------
// Old-style GEMM K-loop core (kept for gemm_oproj), BK=64: As/Bs [128][64] u16
// ---------------------------------------------------------------------------
#define GEMM_BK64_LOOP(Ar, Ai, B2)                                             \
    for (int k0 = 0; k0 < KK; k0 += 64) {                                      \
        const u16* Asrc = (k0 < EE) ? (Ar + k0) : (Ai + (k0 - EE));            \
        const u16* Bsrc = B2 + k0;                                             \
        __syncthreads();                                                       \
        {                                                                      \
            int rr = lane >> 3, cg = (lane & 7) ^ rr;                          \
            for (int t = 0; t < 4; t++) {                                      \
                int s = wave * 4 + t;                                          \
                int r0 = s * 8 + rr;                                           \
                gl2lds16(Asrc + (size_t)(m0 + r0) * EE + cg * 8, &As[s * 512]);\
                gl2lds16(Bsrc + (size_t)(n0 + r0) * KK + cg * 8, &Bs[s * 512]);\
            }                                                                  \
        }                                                                      \
        __syncthreads();                                                       \
        for (int ks2 = 0; ks2 < 2; ks2++) {                                    \
            bf16x8 a[4], b[4];                                                 \
            for (int t = 0; t < 4; t++) {                                      \
                int ra = wm + t * 16 + l16;                                    \
                a[t] = *(const bf16x8*)&As[ra * 64 + (((ks2 * 4 + quad) ^ (ra & 7)) << 3)]; \
                int rb = wn + t * 16 + l16;                                    \
                b[t] = *(const bf16x8*)&Bs[rb * 64 + (((ks2 * 4 + quad) ^ (rb & 7)) << 3)]; \
            }                                                                  \
            for (int i = 0; i < 4; i++)                                        \
                for (int j = 0; j < 4; j++)                                    \
                    acc[i][j] = __builtin_amdgcn_mfma_f32_16x16x32_bf16(a[i], b[j], acc[i][j], 0, 0, 0); \
        }                                                                      \
    }

// ---------------------------------------------------------------------------
// 256x256 8-phase QKV projection GEMM: grid (8, 16, 3), 512 threads.
// z=0 (Q) / z=1 (K): epilogue -> ws[bh][l][128] bf16 (Q scaled by oscale)
// z=2 (V):           epilogue -> ws[bh][128][2048] bf16 (transposed)
// ---------------------------------------------------------------------------
struct QKVArgs {
    const u16* Ar[3]; const u16* Ai[3]; const u16* B2[3];
    const float* br[3]; const float* bi[3];
    u16* out[3];
    float oscale[3];
};

// barriers: memory clobber pins LDS/global ordering into phases; the vmcnt
// precedes s_barrier inside ONE asm so the count is globalized by the barrier.
#define BAR      asm volatile("s_barrier" ::: "memory")
#define BARW(N)  asm volatile("s_waitcnt vmcnt(" #N ")\n\ts_barrier" ::: "memory")

// register-fragment loads from swizzled LDS halves (conflict-free:
// phys chunk = (s*4+quad) ^ (row&7), row&7 == l16&7 here)
#define LOAD_A(QM)                                                             \
    { const u16* base_ = &AB[buf][0][QM][0];                                   \
      _Pragma("unroll") for (int i_ = 0; i_ < 4; i_++) {                       \
          int row_ = wr * 64 + i_ * 16 + l16;                                  \
          _Pragma("unroll") for (int s_ = 0; s_ < 2; s_++) {                   \
              int ph_ = (s_ * 4 + quad) ^ (l16 & 7);                           \
              afr[i_][s_] = *(const bf16x8*)&base_[row_ * 64 + ph_ * 8];       \
          } } }

#define LOAD_B(QN)                                                             \
    { const u16* base_ = &AB[buf][1][QN][0];                                   \
      _Pragma("unroll") for (int j_ = 0; j_ < 2; j_++) {                       \
          int row_ = wc * 32 + j_ * 16 + l16;                                  \
          _Pragma("unroll") for (int s_ = 0; s_ < 2; s_++) {                   \
              int ph_ = (s_ * 4 + quad) ^ (l16 & 7);                           \
              bfr[QN][j_][s_] = *(const bf16x8*)&base_[row_ * 64 + ph_ * 8];   \
          } } }

#define MMA(QM, QN)                                                            \
    { __builtin_amdgcn_s_setprio(1);                                           \
      _Pragma("unroll") for (int s_ = 0; s_ < 2; s_++)                         \
          _Pragma("unroll") for (int i_ = 0; i_ < 4; i_++)                     \
              _Pragma("unroll") for (int j_ = 0; j_ < 2; j_++)                 \
                  acc[QM * 4 + i_][QN * 2 + j_] =                              \
                      __builtin_amdgcn_mfma_f32_16x16x32_bf16(                 \
                          afr[i_][s_], bfr[QN][j_][s_],                        \
                          acc[QM * 4 + i_][QN * 2 + j_], 0, 0, 0);             \
      __builtin_amdgcn_s_setprio(0); }

// stage one 128x64 half-tile (16 KB) = 2 gl2lds/thread; LDS dest linear,
// source chunk pre-swizzled so LDS[row][c] = G[row][c ^ (row&7)].
#define STAGE_A(BUF, HALF, K0)                                                 \
    { const u16* S_ = ((K0) < EE) ? (Apr + (K0)) : (Api + ((K0) - EE));        \
      int rl_ = wv * 8 + (lane >> 3);                                          \
      int cg_ = ((lane & 7) ^ (lane >> 3)) * 8;                                \
      gl2lds16(S_ + (size_t)(m0 + (HALF) * 128 + rl_) * EE + cg_,              \
               &AB[BUF][0][HALF][wv * 512]);                                   \
      gl2lds16(S_ + (size_t)(m0 + (HALF) * 128 + rl_ + 64) * EE + cg_,         \
               &AB[BUF][0][HALF][wv * 512 + 4096]); }

#define STAGE_B(BUF, HALF, K0)                                                 \
    { const u16* S_ = Bp + (K0);                                               \
      int rl_ = wv * 8 + (lane >> 3);                                          \
      int cg_ = ((lane & 7) ^ (lane >> 3)) * 8;                                \
      gl2lds16(S_ + (size_t)(n0 + (HALF) * 128 + rl_) * (size_t)KK + cg_,      \
               &AB[BUF][1][HALF][wv * 512]);                                   \
      gl2lds16(S_ + (size_t)(n0 + (HALF) * 128 + rl_ + 64) * (size_t)KK + cg_, \
               &AB[BUF][1][HALF][wv * 512 + 4096]); }

__launch_bounds__(512, 2)
__global__ void gemm_qkv(QKVArgs args) {
    // [buf][A=0/B=1][half][128*64] = 128 KiB; buf0 = even K-tiles, buf1 = odd
    __shared__ __attribute__((aligned(16))) u16 AB[2][2][2][8192];

    const int z = blockIdx.z;
    const u16* __restrict__ Apr = args.Ar[z];
    const u16* __restrict__ Api = args.Ai[z];
    const u16* __restrict__ Bp  = args.B2[z];

    const int tid = threadIdx.x, wv = tid >> 6, lane = tid & 63;
    const int quad = lane >> 4, l16 = lane & 15;
    const int m0 = blockIdx.y * 256, n0 = blockIdx.x * 256;
    const int wr = wv >> 2, wc = wv & 3;   // 2M x 4N waves, 128x64 out each

    f32x4 acc[8][4] = {};
    bf16x8 afr[4][2];        // current A-half frags: [rowfrag][ksub]
    bf16x8 bfr[2][2][2];     // both B-halves:        [qn][colfrag][ksub]

    // prologue: stage K-tile 0 -> buf0, K-tile 1 -> buf1 (16 loads/thread)
    STAGE_A(0, 0, 0);  STAGE_B(0, 0, 0);  STAGE_B(0, 1, 0);  STAGE_A(0, 1, 0);
    STAGE_A(1, 0, 64); STAGE_B(1, 0, 64); STAGE_B(1, 1, 64); STAGE_A(1, 1, 64);
    BARW(8);                 // tile 0 fully resident everywhere; tile 1 in flight

    // main loop: iteration T2 computes K-tiles 2*T2 (buf0) and 2*T2+1 (buf1),
    // stages K-tiles 2*T2+2 (buf0) and 2*T2+3 (buf1). One barrier per phase;
    // each stage targets a region whose last ds-read was the PREVIOUS phase
    // (the phase barrier makes this race-free). vmcnt(8) at ph4 completes the
    // odd tile staged last iteration; at ph8 completes the next even tile.
    for (int T2 = 0; T2 < 15; T2++) {
        const int ke = (2 * T2 + 2) * 64, ko = (2 * T2 + 3) * 64;
        {   // ---- even K-tile: buf0 ----
            const int buf = 0;
            LOAD_A(0); LOAD_B(0);                      // ph1: reads A0,B0
            BAR;  MMA(0, 0);
            LOAD_B(1);                                 // ph2: reads B1
            STAGE_A(0, 0, ke); STAGE_B(0, 0, ke);      //   stage A0,B0 (read ph1)
            BAR;  MMA(0, 1);
            LOAD_A(1);                                 // ph3: reads A1
            STAGE_B(0, 1, ke);                         //   stage B1 (read ph2)
            BAR;  MMA(1, 1);
            STAGE_A(0, 1, ke);                         // ph4: stage A1 (read ph3)
            BARW(8);                                   //   odd tile (prev iter) resident
            MMA(1, 0);
        }
        {   // ---- odd K-tile: buf1 ----
            const int buf = 1;
            LOAD_A(0); LOAD_B(0);                      // ph5
            BAR;  MMA(0, 0);
            LOAD_B(1);                                 // ph6
            STAGE_A(1, 0, ko); STAGE_B(1, 0, ko);
            BAR;  MMA(0, 1);
            LOAD_A(1);                                 // ph7
            STAGE_B(1, 1, ko);
            BAR;  MMA(1, 1);
            STAGE_A(1, 1, ko);                         // ph8
            BARW(8);                                   //   next even tile resident
            MMA(1, 0);
        }
    }
    {   // peeled last iteration: K-tiles 30 (buf0, resident) and 31 (buf1)
        {
            const int buf = 0;
            LOAD_A(0); LOAD_B(0); MMA(0, 0);
            LOAD_B(1);            MMA(0, 1);
            LOAD_A(1);            MMA(1, 1);
                                  MMA(1, 0);
        }
        BARW(0);                 // drain: tile 31 resident everywhere
        {
            const int buf = 1;
            LOAD_A(0); LOAD_B(0); MMA(0, 0);
            LOAD_B(1);            MMA(0, 1);
            LOAD_A(1);            MMA(1, 1);
                                  MMA(1, 0);
        }
    }

    // epilogue
    const float* __restrict__ br_ = args.br[z];
    const float* __restrict__ bi_ = args.bi[z];
    u16* __restrict__ out = args.out[z];
    const float oscale = args.oscale[z];

    #pragma unroll
    for (int j = 0; j < 4; j++) {
        int gn = n0 + (j >> 1) * 128 + wc * 32 + (j & 1) * 16 + l16;
        int ri = gn >> 10, e = gn & 1023;
        float bias = ri ? bi_[e] : br_[e];
        int h = e >> 6, d = e & 63;
        #pragma unroll
        for (int i = 0; i < 8; i++) {
            int gmb = m0 + (i >> 2) * 128 + wr * 64 + (i & 3) * 16 + quad * 4;
            #pragma unroll
            for (int r = 0; r < 4; r++) {
                int gm = gmb + r;
                float v = (acc[i][j][r] + bias) * oscale;
                int b = gm >> 11, l = gm & 2047;
                if (z < 2)
                    out[((size_t)(b * HH + h) * LL + l) * 128 + ri * 64 + d] = f2bf(v);
                else
                    out[((size_t)(b * HH + h) * 128 + ri * 64 + d) * LL + l] = f2bf(v);
            }
        }
    }
}

// ---------------------------------------------------------------------------
// Output projection GEMM -> d_out fp32 [2][4096][1024]  (unchanged 128² path)
// ---------------------------------------------------------------------------
__launch_bounds__(256, 2)
__global__ void gemm_oproj(const u16* __restrict__ Ar, const u16* __restrict__ Ai,
                           const u16* __restrict__ B2,
                           const float* __restrict__ br, const float* __restrict__ bi,
                           float* __restrict__ out)
{
    __shared__ __attribute__((aligned(16))) u16 As[128 * 64];
    __shared__ __attribute__((aligned(16))) u16 Bs[128 * 64];

    const int tid = threadIdx.x, wave = tid >> 6, lane = tid & 63;
    const int quad = lane >> 4, l16 = lane & 15;
    const int m0 = blockIdx.y * 128, n0 = blockIdx.x * 128;
    const int wm = (wave >> 1) * 64, wn = (wave & 1) * 64;

    f32x4 acc[4][4] = {};

    GEMM_BK64_LOOP(Ar, Ai, B2)

    for (int j = 0; j < 4; j++) {
        int gn = n0 + wn + j * 16 + l16;
        int ri = gn >> 10, e = gn & 1023;
        float bias = ri ? bi[e] : br[e];
        for (int i = 0; i < 4; i++) {
            int gmb = m0 + wm + i * 16 + quad * 4;
            for (int r = 0; r < 4; r++) {
                int gm = gmb + r;
                out[ri * (BL * EE) + gm * EE + e] = acc[i][j][r] + bias;
            }
        }
    }
}

// ---------------------------------------------------------------------------
// Flash attention, BQ=64 (grid 32x32, 3 blocks/CU): transposed-S, online
// softmax in log2 domain (math VERBATIM from the known-good R2 kernel).
// q_ws/k_ws: bf16 [bh][l][128] (Q pre-scaled by 0.125*log2e); v_ws: [bh][128][2048]
// ---------------------------------------------------------------------------
__launch_bounds__(256, 3)
__global__ void attn(const u16* __restrict__ q_ws, const u16* __restrict__ k_ws,
                     const u16* __restrict__ v_ws,
                     u16* __restrict__ o_r, u16* __restrict__ o_i)
{
    __shared__ __attribute__((aligned(16))) u16 kbuf[2][64 * 128];  // 2x16 KB
    __shared__ __attribute__((aligned(16))) u16 vbuf[128 * 64];     // 16 KB
    __shared__ __attribute__((aligned(16))) float red_sh[4][16];

    const int tid = threadIdx.x, wave = tid >> 6, lane = tid & 63;
    const int quad = lane >> 4, l16 = lane & 15;
    const int q0 = blockIdx.x * 64, bh = blockIdx.y;

    // Q fragments (B-operand layout: row = l16, k = quad*8+j); wave owns 16 q rows
    bf16x8 qf[4];
    {
        const u16* qp = q_ws + (size_t)(bh * LL + q0 + wave * 16 + l16) * 128 + quad * 8;
        for (int ks = 0; ks < 4; ks++)
            qf[ks] = *(const bf16x8*)(qp + ks * 32);
    }

    auto stage_k = [&](int nb, int kv0) {
        for (int t = 0; t < 4; t++) {
            int s = wave * 4 + t;
            int row = s * 4 + (lane >> 4);
            int cg = (lane & 15) ^ (row & 15);
            gl2lds16(k_ws + (size_t)(bh * LL + kv0 + row) * 128 + cg * 8, &kbuf[nb][s * 512]);
        }
    };
    auto stage_v = [&](int kv0) {
        for (int t = 0; t < 4; t++) {
            int s = wave * 4 + t;
            int row = s * 8 + (lane >> 3);
            int cg = (lane & 7) ^ (row & 7);
            gl2lds16(v_ws + (size_t)(bh * 128 + row) * LL + kv0 + cg * 8, &vbuf[s * 512]);
        }
    };

    stage_k(0, 0);
    stage_v(0);
    stage_k(1, 64);
    __syncthreads();

    f32x4 oacc[8] = {};
    float m_st = -__builtin_inff();
    float l_st = 0.f;

    for (int N = 0; N < 32; N++) {
        const int cur = N & 1;
        u16* K = kbuf[cur];

        // ---- S^T[64 kv][16 q] = K . Q^T ----
        f32x4 s[4] = {};
        for (int ks = 0; ks < 4; ks++) {
            bf16x8 kf[4];
            for (int mt = 0; mt < 4; mt++) {
                int row = mt * 16 + l16;
                int cl = (ks * 4 + quad) ^ (row & 15);
                kf[mt] = *(const bf16x8*)&K[row * 128 + cl * 8];
            }
            for (int mt = 0; mt < 4; mt++)
                s[mt] = __builtin_amdgcn_mfma_f32_16x16x32_bf16(kf[mt], qf[ks], s[mt], 0, 0, 0);
        }

        // ---- online softmax (log2 domain); q = l16, kv = mt*16+quad*4+r ----
        bool changed = false;
        float alpha;
        {
            float mx = -__builtin_inff();
            for (int mt = 0; mt < 4; mt++)
                for (int r = 0; r < 4; r++)
                    mx = fmaxf(mx, s[mt][r]);
            mx = fmaxf(mx, __shfl_xor(mx, 16, 64));
            mx = fmaxf(mx, __shfl_xor(mx, 32, 64));
            float mnew = fmaxf(m_st, mx);
            changed = (mnew != m_st);
            alpha = __builtin_amdgcn_exp2f(m_st - mnew);
            m_st = mnew;
            float sum = 0.f;
            for (int mt = 0; mt < 4; mt++)
                for (int r = 0; r < 4; r++) {
                    float p = __builtin_amdgcn_exp2f(s[mt][r] - mnew);
                    s[mt][r] = p;
                    sum += p;
                }
            sum += __shfl_xor(sum, 16, 64);
            sum += __shfl_xor(sum, 32, 64);
            l_st = l_st * alpha + sum;
            if (quad == 0) red_sh[wave][l16] = alpha;
        }
        __syncthreads();   // barrier A: K[cur] reads done; drains prev async loads

        // ---- P (A-layout [16 q][64 kv]) into own slice of kbuf[cur] ----
        u16* P = kbuf[cur] + wave * 1024;
        for (int mt = 0; mt < 4; mt++) {
            int q = l16;
            int cg = mt * 2 + (quad >> 1);
            int cl = cg ^ (q & 7);
            ushort4 pk;
            pk.x = f2bf(s[mt][0]); pk.y = f2bf(s[mt][1]);
            pk.z = f2bf(s[mt][2]); pk.w = f2bf(s[mt][3]);
            *(ushort4*)&P[q * 64 + cl * 8 + (quad & 1) * 4] = pk;
        }

        // ---- O rescale (skip when running max unchanged wave-wide) ----
        if (__any(changed)) {
            f32x4 av = *(const f32x4*)&red_sh[wave][quad * 4];
            for (int nt = 0; nt < 8; nt++)
                oacc[nt] *= av;
        }

        // ---- O += P @ V ----
        for (int ks = 0; ks < 2; ks++) {
            int clp = (ks * 4 + quad) ^ (l16 & 7);
            bf16x8 pf = *(const bf16x8*)&P[l16 * 64 + clp * 8];
            for (int nt = 0; nt < 8; nt++) {
                int row = nt * 16 + l16;
                int cl = (ks * 4 + quad) ^ (row & 7);
                bf16x8 vf = *(const bf16x8*)&vbuf[row * 64 + cl * 8];
                oacc[nt] = __builtin_amdgcn_mfma_f32_16x16x32_bf16(pf, vf, oacc[nt], 0, 0, 0);
            }
        }
        __syncthreads();   // barrier B: PV done everywhere; P dead, vbuf free

        if (N + 2 < 32) stage_k(cur, (N + 2) * 64);   // into region P occupied
        if (N + 1 < 32) stage_v((N + 1) * 64);
    }

    // ---- epilogue: O /= l, write bf16 o_r/o_i [4096][1024] ----
    if (quad == 0) red_sh[wave][l16] = l_st;
    __syncthreads();
    f32x4 lv = *(const f32x4*)&red_sh[wave][quad * 4];
    f32x4 inv;
    for (int r = 0; r < 4; r++) inv[r] = 1.0f / lv[r];
    const int b = bh >> 4, h = bh & 15;
    for (int nt = 0; nt < 8; nt++) {
        int d2 = nt * 16 + l16;
        u16* op = (d2 < 64) ? o_r : o_i;
        int col = h * 64 + (d2 & 63);
        for (int r = 0; r < 4; r++) {
            int l = q0 + wave * 16 + quad * 4 + r;
            op[(size_t)(b * LL + l) * EE + col] = f2bf(oacc[nt][r] * inv[r]);
        }
    }
}

// ---------------------------------------------------------------------------
extern "C" void kernel_launch(void* const* d_in, const int* in_sizes, int n_in,
                              void* d_out, int out_size, void* d_ws, size_t ws_size,
                              hipStream_t stream) {
    const float* bq_r = (const float*)d_in[8];
    const float* bq_i = (const float*)d_in[9];
    const float* bk_r = (const float*)d_in[12];
    const float* bk_i = (const float*)d_in[13];
    const float* bv_r = (const float*)d_in[16];
    const float* bv_i = (const float*)d_in[17];
    const float* bo_r = (const float*)d_in[20];
    const float* bo_i = (const float*)d_in[21];

    u16* ws = (u16*)d_ws;
    const size_t XN = 4194304;          // 4096*1024 elements (= 2048*2048)
    u16* xqr = ws;            u16* xqi = xqr + XN;
    u16* xkr = xqi + XN;      u16* xki = xkr + XN;
    u16* xvr = xki + XN;      u16* xvi = xvr + XN;
    u16* w2q = xvi + XN;
    u16* w2k = w2q + XN;
    u16* w2v = w2k + XN;
    u16* w2o = w2v + XN;
    u16* q_ws = w2o + XN;               // 32*2048*128 = 8,388,608
    u16* k_ws = q_ws + 8388608;
    u16* v_ws = k_ws + 8388608;
    u16* o_r = xqr;                     // X regions dead after QKV GEMMs
    u16* o_i = xqr + XN;

    dim3 blk(256);

    ConvXArgs cx;
    cx.src[0] = (const float*)d_in[0]; cx.dst[0] = xqr;
    cx.src[1] = (const float*)d_in[1]; cx.dst[1] = xqi;
    cx.src[2] = (const float*)d_in[2]; cx.dst[2] = xkr;
    cx.src[3] = (const float*)d_in[3]; cx.dst[3] = xki;
    cx.src[4] = (const float*)d_in[4]; cx.dst[4] = xvr;
    cx.src[5] = (const float*)d_in[5]; cx.dst[5] = xvi;
    conv_x<<<dim3(4096, 6), blk, 0, stream>>>(cx);

    ConvWArgs cw;
    cw.wr[0] = (const float*)d_in[6];  cw.wi[0] = (const float*)d_in[7];  cw.w2[0] = w2q;
    cw.wr[1] = (const float*)d_in[10]; cw.wi[1] = (const float*)d_in[11]; cw.w2[1] = w2k;
    cw.wr[2] = (const float*)d_in[14]; cw.wi[2] = (const float*)d_in[15]; cw.w2[2] = w2v;
    cw.wr[3] = (const float*)d_in[18]; cw.wi[3] = (const float*)d_in[19]; cw.w2[3] = w2o;
    conv_w<<<dim3(4096, 4), blk, 0, stream>>>(cw);

    const float QSCALE = 0.125f * 1.44269504088896f;   // 1/sqrt(D) * log2(e)
    QKVArgs qa;
    qa.Ar[0] = xqr; qa.Ai[0] = xqi; qa.B2[0] = w2q; qa.br[0] = bq_r; qa.bi[0] = bq_i; qa.out[0] = q_ws; qa.oscale[0] = QSCALE;
    qa.Ar[1] = xkr; qa.Ai[1] = xki; qa.B2[1] = w2k; qa.br[1] = bk_r; qa.bi[1] = bk_i; qa.out[1] = k_ws; qa.oscale[1] = 1.0f;
    qa.Ar[2] = xvr; qa.Ai[2] = xvi; qa.B2[2] = w2v; qa.br[2] = bv_r; qa.bi[2] = bv_i; qa.out[2] = v_ws; qa.oscale[2] = 1.0f;
    gemm_qkv<<<dim3(8, 16, 3), dim3(512), 0, stream>>>(qa);

    attn<<<dim3(32, 32), blk, 0, stream>>>(q_ws, k_ws, v_ws, o_r, o_i);

    gemm_oproj<<<dim3(16, 32), blk, 0, stream>>>(o_r, o_i, w2o, bo_r, bo_i, (float*)d_out);
}

// Round 3
// 477.279 us; speedup vs baseline: 1.0327x; 1.0189x over previous
//
#include <hip/hip_runtime.h>

// ComplexMultiheadAttention on MI355X (gfx950)  B=2, L=2048, E=1024, H=16, D=64
// R9: GEMMs re-tiled 128x256 (BK=64, 512 thr, wave tile 64x64) so the grid
// packs the CUs exactly: qkv = 256 tiles/z * 3 = 768 blocks = 3 clean rounds
// at 1 block/CU; oproj = 256 blocks = 1 round. Triple-buffered LDS
// (3 x 48 KiB = 144 KiB) gives T4 wait depth without 2-tile unroll: iter T
// computes tile T, stages tile T+2, end-of-iter vmcnt(6) waits only tile T+1
// (issued a full iteration earlier; tile T+2's 6 loads stay in flight).
// 2 phases per K-tile (B-half quadrants), setprio around MFMA clusters,
// XOR-swizzled LDS (conflict-free, proven R8). Per-element MFMA K-chain
// order unchanged -> bit-identical numerics (absmax 0.0390625).
// attn / conv_x / conv_w unchanged.

#define LL 2048
#define EE 1024
#define HH 16
#define BL 4096   // B*L
#define KK 2048   // GEMM K (re||im)

typedef __attribute__((ext_vector_type(8))) short bf16x8;
typedef __attribute__((ext_vector_type(4))) float f32x4;
typedef unsigned short u16;

__device__ __forceinline__ u16 f2bf(float x) {
    unsigned u = __builtin_bit_cast(unsigned, x);
    u += 0x7fff + ((u >> 16) & 1);          // RNE
    return (u16)(u >> 16);
}

__device__ __forceinline__ void gl2lds16(const void* g, void* l) {
    __builtin_amdgcn_global_load_lds((const __attribute__((address_space(1))) void*)g,
                                     (__attribute__((address_space(3))) void*)l, 16, 0, 0);
}

// ---------------------------------------------------------------------------
// Merged fp32->bf16 conversion: 6 activation tensors, grid (4096, 6)
// ---------------------------------------------------------------------------
struct ConvXArgs { const float* src[6]; u16* dst[6]; };
__global__ void conv_x(ConvXArgs a) {
    const int z = blockIdx.y;
    int i = blockIdx.x * 256 + threadIdx.x;     // 1,048,576 float4 groups exactly
    float4 v = ((const float4*)a.src[z])[i];
    ushort4 o;
    o.x = f2bf(v.x); o.y = f2bf(v.y); o.z = f2bf(v.z); o.w = f2bf(v.w);
    ((ushort4*)a.dst[z])[i] = o;
}

// ---------------------------------------------------------------------------
// Merged W2 build: 4 weight pairs, grid (4096, 4)
// W2 bf16 [2048 n][2048 k]: n<1024: [Wr | -Wi] ; n>=1024: [Wi | Wr]
// ---------------------------------------------------------------------------
struct ConvWArgs { const float* wr[4]; const float* wi[4]; u16* w2[4]; };
__global__ void conv_w(ConvWArgs a) {
    const int z = blockIdx.y;
    int i = blockIdx.x * 256 + threadIdx.x;     // 2048*512 groups exactly
    int n = i >> 9, k = (i & 511) << 2;
    bool nh = n >= EE, kh = k >= EE;
    int nn = n & (EE - 1), kk = k & (EE - 1);
    const float* src = nh ? (kh ? a.wr[z] : a.wi[z]) : (kh ? a.wi[z] : a.wr[z]);
    float sgn = (!nh && kh) ? -1.0f : 1.0f;
    float4 v = *(const float4*)(src + nn * EE + kk);
    ushort4 o;
    o.x = f2bf(v.x * sgn); o.y = f2bf(v.y * sgn);
    o.z = f2bf(v.z * sgn); o.w = f2bf(v.w * sgn);
    *(ushort4*)(a.w2[z] + n * KK + k) = o;
}

// ---------------------------------------------------------------------------
// Shared 128x256 triple-buffered GEMM K-loop.
// LDS: As3[3][128*64] (16 KB/buf) + Bs3[3][256*64] (32 KB/buf) = 144 KiB.
// 512 threads = 8 waves as 2M x 4N; wave tile 64x64 = acc[4][4] (64 VGPR).
// acc[i][j]: row m0+wr*64+i*16+(quad*4+r), col n0+(j>>1)*128+wc*32+(j&1)*16+l16.
// Swizzle: LDS[row][phys chunk c] holds global chunk c ^ (row&7) (16B chunks).
// ---------------------------------------------------------------------------
#define BAR      asm volatile("s_barrier" ::: "memory")
#define BARW(N)  asm volatile("s_waitcnt vmcnt(" #N ")\n\ts_barrier" ::: "memory")

// stage A tile (128 rows x 64 k) of K-slice K0 into buf B: 2 loads/thread
#define S_A(B, K0)                                                             \
    { const u16* S_ = ((K0) < EE) ? (Apr + (K0)) : (Api + ((K0) - EE));        \
      int rl_ = wv * 8 + (lane >> 3);                                          \
      int cg_ = ((lane & 7) ^ (lane >> 3)) * 8;                                \
      gl2lds16(S_ + (size_t)(m0 + rl_) * EE + cg_, &As3[B][wv * 512]);         \
      gl2lds16(S_ + (size_t)(m0 + rl_ + 64) * EE + cg_, &As3[B][wv * 512 + 4096]); }

// stage B half H (128 rows x 64 k) of K-slice K0 into buf B: 2 loads/thread
#define S_B(B, H, K0)                                                          \
    { const u16* S_ = Bp + (K0);                                               \
      int rl_ = wv * 8 + (lane >> 3);                                          \
      int cg_ = ((lane & 7) ^ (lane >> 3)) * 8;                                \
      gl2lds16(S_ + (size_t)(n0 + (H) * 128 + rl_) * (size_t)KK + cg_,         \
               &Bs3[B][(H) * 8192 + wv * 512]);                                \
      gl2lds16(S_ + (size_t)(n0 + (H) * 128 + rl_ + 64) * (size_t)KK + cg_,    \
               &Bs3[B][(H) * 8192 + wv * 512 + 4096]); }

// register-fragment loads (conflict-free: phys = logical ^ (row&7), row&7==l16&7)
#define L_A(B)                                                                 \
    _Pragma("unroll") for (int i_ = 0; i_ < 4; i_++) {                         \
        int row_ = wr * 64 + i_ * 16 + l16;                                    \
        _Pragma("unroll") for (int s_ = 0; s_ < 2; s_++) {                     \
            int ph_ = (s_ * 4 + quad) ^ (l16 & 7);                             \
            afr[i_][s_] = *(const bf16x8*)&As3[B][row_ * 64 + ph_ * 8]; } }

#define L_B(B, H)                                                              \
    _Pragma("unroll") for (int j_ = 0; j_ < 2; j_++) {                         \
        int row_ = wc * 32 + j_ * 16 + l16;                                    \
        _Pragma("unroll") for (int s_ = 0; s_ < 2; s_++) {                     \
            int ph_ = (s_ * 4 + quad) ^ (l16 & 7);                             \
            bfr[j_][s_] = *(const bf16x8*)&Bs3[B][(H) * 8192 + row_ * 64 + ph_ * 8]; } }

#define MMA_H(H)                                                               \
    { __builtin_amdgcn_s_setprio(1);                                           \
      _Pragma("unroll") for (int s_ = 0; s_ < 2; s_++)                         \
          _Pragma("unroll") for (int i_ = 0; i_ < 4; i_++)                     \
              _Pragma("unroll") for (int j_ = 0; j_ < 2; j_++)                 \
                  acc[i_][(H) * 2 + j_] =                                      \
                      __builtin_amdgcn_mfma_f32_16x16x32_bf16(                 \
                          afr[i_][s_], bfr[j_][s_], acc[i_][(H) * 2 + j_], 0, 0, 0); \
      __builtin_amdgcn_s_setprio(0); }

// one K-tile: compute buf B, stage K-slice KN into buf NB, wait tile T+1 only
#define GITER(B, NB, KN)                                                       \
    {   L_A(B); L_B(B, 0);                                                     \
        S_A(NB, KN); S_B(NB, 0, KN);                                           \
        BAR;                                                                   \
        MMA_H(0);                                                              \
        L_B(B, 1);                                                             \
        S_B(NB, 1, KN);                                                        \
        BAR;                                                                   \
        MMA_H(1);                                                              \
        BARW(6); }

// full 32-K-tile loop: prologue stages tiles 0,1; T=0..29 via GITER;
// peeled T=30 (drain to 0) and T=31.
#define GEMM3_LOOP                                                             \
    S_A(0, 0);  S_B(0, 0, 0);  S_B(0, 1, 0);                                   \
    S_A(1, 64); S_B(1, 0, 64); S_B(1, 1, 64);                                  \
    BARW(6);                                                                   \
    for (int t3 = 0; t3 < 10; t3++) {                                          \
        const int kb = t3 * 192;                                               \
        GITER(0, 2, kb + 128);                                                 \
        GITER(1, 0, kb + 192);                                                 \
        GITER(2, 1, kb + 256);                                                 \
    }                                                                          \
    { L_A(0); L_B(0, 0); MMA_H(0); L_B(0, 1); MMA_H(1); }                      \
    BARW(0);                                                                   \
    { L_A(1); L_B(1, 0); MMA_H(0); L_B(1, 1); MMA_H(1); }

// ---------------------------------------------------------------------------
// Merged Q/K/V projection GEMM: grid (8, 32, 3), 512 threads.
// z=0 (Q) / z=1 (K): epilogue -> ws[bh][l][128] bf16 (Q scaled by oscale)
// z=2 (V):           epilogue -> ws[bh][128][2048] bf16 (transposed)
// ---------------------------------------------------------------------------
struct QKVArgs {
    const u16* Ar[3]; const u16* Ai[3]; const u16* B2[3];
    const float* br[3]; const float* bi[3];
    u16* out[3];
    float oscale[3];
};

__launch_bounds__(512, 1)
__global__ void gemm_qkv(QKVArgs args) {
    __shared__ __attribute__((aligned(16))) u16 As3[3][128 * 64];
    __shared__ __attribute__((aligned(16))) u16 Bs3[3][256 * 64];

    const int z = blockIdx.z;
    const u16* __restrict__ Apr = args.Ar[z];
    const u16* __restrict__ Api = args.Ai[z];
    const u16* __restrict__ Bp  = args.B2[z];

    const int tid = threadIdx.x, wv = tid >> 6, lane = tid & 63;
    const int quad = lane >> 4, l16 = lane & 15;
    const int m0 = blockIdx.y * 128, n0 = blockIdx.x * 256;
    const int wr = wv >> 2, wc = wv & 3;   // 2M x 4N waves, 64x64 out each

    f32x4 acc[4][4] = {};
    bf16x8 afr[4][2];
    bf16x8 bfr[2][2];

    GEMM3_LOOP

    const float* __restrict__ br_ = args.br[z];
    const float* __restrict__ bi_ = args.bi[z];
    u16* __restrict__ out = args.out[z];
    const float oscale = args.oscale[z];

    #pragma unroll
    for (int j = 0; j < 4; j++) {
        int gn = n0 + (j >> 1) * 128 + wc * 32 + (j & 1) * 16 + l16;
        int ri = gn >> 10, e = gn & 1023;
        float bias = ri ? bi_[e] : br_[e];
        int h = e >> 6, d = e & 63;
        #pragma unroll
        for (int i = 0; i < 4; i++) {
            int gmb = m0 + wr * 64 + i * 16 + quad * 4;
            #pragma unroll
            for (int r = 0; r < 4; r++) {
                int gm = gmb + r;
                float v = (acc[i][j][r] + bias) * oscale;
                int b = gm >> 11, l = gm & 2047;
                if (z < 2)
                    out[((size_t)(b * HH + h) * LL + l) * 128 + ri * 64 + d] = f2bf(v);
                else
                    out[((size_t)(b * HH + h) * 128 + ri * 64 + d) * LL + l] = f2bf(v);
            }
        }
    }
}

// ---------------------------------------------------------------------------
// Output projection GEMM -> d_out fp32 [2][4096][1024]: grid (8, 32), 512 thr
// (256 blocks = exactly 1 round at 1 block/CU)
// ---------------------------------------------------------------------------
__launch_bounds__(512, 1)
__global__ void gemm_oproj(const u16* __restrict__ Ar, const u16* __restrict__ Ai,
                           const u16* __restrict__ B2,
                           const float* __restrict__ br, const float* __restrict__ bi,
                           float* __restrict__ out)
{
    __shared__ __attribute__((aligned(16))) u16 As3[3][128 * 64];
    __shared__ __attribute__((aligned(16))) u16 Bs3[3][256 * 64];

    const u16* __restrict__ Apr = Ar;
    const u16* __restrict__ Api = Ai;
    const u16* __restrict__ Bp  = B2;

    const int tid = threadIdx.x, wv = tid >> 6, lane = tid & 63;
    const int quad = lane >> 4, l16 = lane & 15;
    const int m0 = blockIdx.y * 128, n0 = blockIdx.x * 256;
    const int wr = wv >> 2, wc = wv & 3;

    f32x4 acc[4][4] = {};
    bf16x8 afr[4][2];
    bf16x8 bfr[2][2];

    GEMM3_LOOP

    #pragma unroll
    for (int j = 0; j < 4; j++) {
        int gn = n0 + (j >> 1) * 128 + wc * 32 + (j & 1) * 16 + l16;
        int ri = gn >> 10, e = gn & 1023;
        float bias = ri ? bi[e] : br[e];
        #pragma unroll
        for (int i = 0; i < 4; i++) {
            int gmb = m0 + wr * 64 + i * 16 + quad * 4;
            #pragma unroll
            for (int r = 0; r < 4; r++) {
                int gm = gmb + r;
                out[ri * (BL * EE) + gm * EE + e] = acc[i][j][r] + bias;
            }
        }
    }
}

// ---------------------------------------------------------------------------
// Flash attention, BQ=64 (grid 32x32, 3 blocks/CU): transposed-S, online
// softmax in log2 domain (math VERBATIM from the known-good R2 kernel).
// q_ws/k_ws: bf16 [bh][l][128] (Q pre-scaled by 0.125*log2e); v_ws: [bh][128][2048]
// ---------------------------------------------------------------------------
__launch_bounds__(256, 3)
__global__ void attn(const u16* __restrict__ q_ws, const u16* __restrict__ k_ws,
                     const u16* __restrict__ v_ws,
                     u16* __restrict__ o_r, u16* __restrict__ o_i)
{
    __shared__ __attribute__((aligned(16))) u16 kbuf[2][64 * 128];  // 2x16 KB
    __shared__ __attribute__((aligned(16))) u16 vbuf[128 * 64];     // 16 KB
    __shared__ __attribute__((aligned(16))) float red_sh[4][16];

    const int tid = threadIdx.x, wave = tid >> 6, lane = tid & 63;
    const int quad = lane >> 4, l16 = lane & 15;
    const int q0 = blockIdx.x * 64, bh = blockIdx.y;

    // Q fragments (B-operand layout: row = l16, k = quad*8+j); wave owns 16 q rows
    bf16x8 qf[4];
    {
        const u16* qp = q_ws + (size_t)(bh * LL + q0 + wave * 16 + l16) * 128 + quad * 8;
        for (int ks = 0; ks < 4; ks++)
            qf[ks] = *(const bf16x8*)(qp + ks * 32);
    }

    auto stage_k = [&](int nb, int kv0) {
        for (int t = 0; t < 4; t++) {
            int s = wave * 4 + t;
            int row = s * 4 + (lane >> 4);
            int cg = (lane & 15) ^ (row & 15);
            gl2lds16(k_ws + (size_t)(bh * LL + kv0 + row) * 128 + cg * 8, &kbuf[nb][s * 512]);
        }
    };
    auto stage_v = [&](int kv0) {
        for (int t = 0; t < 4; t++) {
            int s = wave * 4 + t;
            int row = s * 8 + (lane >> 3);
            int cg = (lane & 7) ^ (row & 7);
            gl2lds16(v_ws + (size_t)(bh * 128 + row) * LL + kv0 + cg * 8, &vbuf[s * 512]);
        }
    };

    stage_k(0, 0);
    stage_v(0);
    stage_k(1, 64);
    __syncthreads();

    f32x4 oacc[8] = {};
    float m_st = -__builtin_inff();
    float l_st = 0.f;

    for (int N = 0; N < 32; N++) {
        const int cur = N & 1;
        u16* K = kbuf[cur];

        // ---- S^T[64 kv][16 q] = K . Q^T ----
        f32x4 s[4] = {};
        for (int ks = 0; ks < 4; ks++) {
            bf16x8 kf[4];
            for (int mt = 0; mt < 4; mt++) {
                int row = mt * 16 + l16;
                int cl = (ks * 4 + quad) ^ (row & 15);
                kf[mt] = *(const bf16x8*)&K[row * 128 + cl * 8];
            }
            for (int mt = 0; mt < 4; mt++)
                s[mt] = __builtin_amdgcn_mfma_f32_16x16x32_bf16(kf[mt], qf[ks], s[mt], 0, 0, 0);
        }

        // ---- online softmax (log2 domain); q = l16, kv = mt*16+quad*4+r ----
        bool changed = false;
        float alpha;
        {
            float mx = -__builtin_inff();
            for (int mt = 0; mt < 4; mt++)
                for (int r = 0; r < 4; r++)
                    mx = fmaxf(mx, s[mt][r]);
            mx = fmaxf(mx, __shfl_xor(mx, 16, 64));
            mx = fmaxf(mx, __shfl_xor(mx, 32, 64));
            float mnew = fmaxf(m_st, mx);
            changed = (mnew != m_st);
            alpha = __builtin_amdgcn_exp2f(m_st - mnew);
            m_st = mnew;
            float sum = 0.f;
            for (int mt = 0; mt < 4; mt++)
                for (int r = 0; r < 4; r++) {
                    float p = __builtin_amdgcn_exp2f(s[mt][r] - mnew);
                    s[mt][r] = p;
                    sum += p;
                }
            sum += __shfl_xor(sum, 16, 64);
            sum += __shfl_xor(sum, 32, 64);
            l_st = l_st * alpha + sum;
            if (quad == 0) red_sh[wave][l16] = alpha;
        }
        __syncthreads();   // barrier A: K[cur] reads done; drains prev async loads

        // ---- P (A-layout [16 q][64 kv]) into own slice of kbuf[cur] ----
        u16* P = kbuf[cur] + wave * 1024;
        for (int mt = 0; mt < 4; mt++) {
            int q = l16;
            int cg = mt * 2 + (quad >> 1);
            int cl = cg ^ (q & 7);
            ushort4 pk;
            pk.x = f2bf(s[mt][0]); pk.y = f2bf(s[mt][1]);
            pk.z = f2bf(s[mt][2]); pk.w = f2bf(s[mt][3]);
            *(ushort4*)&P[q * 64 + cl * 8 + (quad & 1) * 4] = pk;
        }

        // ---- O rescale (skip when running max unchanged wave-wide) ----
        if (__any(changed)) {
            f32x4 av = *(const f32x4*)&red_sh[wave][quad * 4];
            for (int nt = 0; nt < 8; nt++)
                oacc[nt] *= av;
        }

        // ---- O += P @ V ----
        for (int ks = 0; ks < 2; ks++) {
            int clp = (ks * 4 + quad) ^ (l16 & 7);
            bf16x8 pf = *(const bf16x8*)&P[l16 * 64 + clp * 8];
            for (int nt = 0; nt < 8; nt++) {
                int row = nt * 16 + l16;
                int cl = (ks * 4 + quad) ^ (row & 7);
                bf16x8 vf = *(const bf16x8*)&vbuf[row * 64 + cl * 8];
                oacc[nt] = __builtin_amdgcn_mfma_f32_16x16x32_bf16(pf, vf, oacc[nt], 0, 0, 0);
            }
        }
        __syncthreads();   // barrier B: PV done everywhere; P dead, vbuf free

        if (N + 2 < 32) stage_k(cur, (N + 2) * 64);   // into region P occupied
        if (N + 1 < 32) stage_v((N + 1) * 64);
    }

    // ---- epilogue: O /= l, write bf16 o_r/o_i [4096][1024] ----
    if (quad == 0) red_sh[wave][l16] = l_st;
    __syncthreads();
    f32x4 lv = *(const f32x4*)&red_sh[wave][quad * 4];
    f32x4 inv;
    for (int r = 0; r < 4; r++) inv[r] = 1.0f / lv[r];
    const int b = bh >> 4, h = bh & 15;
    for (int nt = 0; nt < 8; nt++) {
        int d2 = nt * 16 + l16;
        u16* op = (d2 < 64) ? o_r : o_i;
        int col = h * 64 + (d2 & 63);
        for (int r = 0; r < 4; r++) {
            int l = q0 + wave * 16 + quad * 4 + r;
            op[(size_t)(b * LL + l) * EE + col] = f2bf(oacc[nt][r] * inv[r]);
        }
    }
}

// ---------------------------------------------------------------------------
extern "C" void kernel_launch(void* const* d_in, const int* in_sizes, int n_in,
                              void* d_out, int out_size, void* d_ws, size_t ws_size,
                              hipStream_t stream) {
    const float* bq_r = (const float*)d_in[8];
    const float* bq_i = (const float*)d_in[9];
    const float* bk_r = (const float*)d_in[12];
    const float* bk_i = (const float*)d_in[13];
    const float* bv_r = (const float*)d_in[16];
    const float* bv_i = (const float*)d_in[17];
    const float* bo_r = (const float*)d_in[20];
    const float* bo_i = (const float*)d_in[21];

    u16* ws = (u16*)d_ws;
    const size_t XN = 4194304;          // 4096*1024 elements (= 2048*2048)
    u16* xqr = ws;            u16* xqi = xqr + XN;
    u16* xkr = xqi + XN;      u16* xki = xkr + XN;
    u16* xvr = xki + XN;      u16* xvi = xvr + XN;
    u16* w2q = xvi + XN;
    u16* w2k = w2q + XN;
    u16* w2v = w2k + XN;
    u16* w2o = w2v + XN;
    u16* q_ws = w2o + XN;               // 32*2048*128 = 8,388,608
    u16* k_ws = q_ws + 8388608;
    u16* v_ws = k_ws + 8388608;
    u16* o_r = xqr;                     // X regions dead after QKV GEMMs
    u16* o_i = xqr + XN;

    dim3 blk(256);

    ConvXArgs cx;
    cx.src[0] = (const float*)d_in[0]; cx.dst[0] = xqr;
    cx.src[1] = (const float*)d_in[1]; cx.dst[1] = xqi;
    cx.src[2] = (const float*)d_in[2]; cx.dst[2] = xkr;
    cx.src[3] = (const float*)d_in[3]; cx.dst[3] = xki;
    cx.src[4] = (const float*)d_in[4]; cx.dst[4] = xvr;
    cx.src[5] = (const float*)d_in[5]; cx.dst[5] = xvi;
    conv_x<<<dim3(4096, 6), blk, 0, stream>>>(cx);

    ConvWArgs cw;
    cw.wr[0] = (const float*)d_in[6];  cw.wi[0] = (const float*)d_in[7];  cw.w2[0] = w2q;
    cw.wr[1] = (const float*)d_in[10]; cw.wi[1] = (const float*)d_in[11]; cw.w2[1] = w2k;
    cw.wr[2] = (const float*)d_in[14]; cw.wi[2] = (const float*)d_in[15]; cw.w2[2] = w2v;
    cw.wr[3] = (const float*)d_in[18]; cw.wi[3] = (const float*)d_in[19]; cw.w2[3] = w2o;
    conv_w<<<dim3(4096, 4), blk, 0, stream>>>(cw);

    const float QSCALE = 0.125f * 1.44269504088896f;   // 1/sqrt(D) * log2(e)
    QKVArgs qa;
    qa.Ar[0] = xqr; qa.Ai[0] = xqi; qa.B2[0] = w2q; qa.br[0] = bq_r; qa.bi[0] = bq_i; qa.out[0] = q_ws; qa.oscale[0] = QSCALE;
    qa.Ar[1] = xkr; qa.Ai[1] = xki; qa.B2[1] = w2k; qa.br[1] = bk_r; qa.bi[1] = bk_i; qa.out[1] = k_ws; qa.oscale[1] = 1.0f;
    qa.Ar[2] = xvr; qa.Ai[2] = xvi; qa.B2[2] = w2v; qa.br[2] = bv_r; qa.bi[2] = bv_i; qa.out[2] = v_ws; qa.oscale[2] = 1.0f;
    gemm_qkv<<<dim3(8, 32, 3), dim3(512), 0, stream>>>(qa);

    attn<<<dim3(32, 32), blk, 0, stream>>>(q_ws, k_ws, v_ws, o_r, o_i);

    gemm_oproj<<<dim3(8, 32), dim3(512), 0, stream>>>(o_r, o_i, w2o, bo_r, bo_i, (float*)d_out);
}